// Round 9
// baseline (212.769 us; speedup 1.0000x reference)
//
#include <hip/hip_runtime.h>
#include <hip/hip_bf16.h>

// GCN forward, MI355X. Round 18: R16 structure (measured best) + dispatch
// re-partition by utilization: pure-atomic dispatch 1, converts ride in
// scan's barren dispatch.
//   memset(deg|desc|pooled|cnt)
//   atomic     : pure degree atomics, 4 edges/thread, return -> rank[e]
//   scan(+cvt) : [0,nb) decoupled-lookback scan over (deg+1), writes
//                self-loop CSR slot | [..XC) X->bf16 | [..BW) W canon |
//                [..BB) batch->i32   (converts fill the ~240 idle CUs)
//   fill       : atomic-free scatter  pos = row_ptr[dst] + 1 + rank[e]
//   aggemm0    : agg(Xbf16) 4-deep shfl gather -> @W1 -> +b1,relu -> @W2
//   aggemm x2  : 4-deep shfl gather + LDS tile + MFMA @Wnext
//   agg_pool   : 8-deep direct gather + LDS pool -> atomics
//   final      : 64x16 @ 16x10 linear
//
// Lessons: R5 fuse at AGG grid; R7 no wide-grid threadfence; R10 capture
// degree atomicAdd return as rank; R11 atomic limiter is latency*concurrency;
// R12 scalar b16 LDS scatter ~= serial shfl gather; R13 don't bet on
// unverified HW mappings; R14 keep row gathers coalesced (32B/lane);
// R15 agg chain is LOAD-LATENCY-bound (4-deep pipe +18us); R16 gemm1
// elimination traffic-neutral; R17 depth 8 + reg-broadcast REGRESSED —
// 4-deep shfl at high occupancy is the measured optimum (VGPR/TLP beats
// deeper ILP). Structure converged; remaining levers are utilization crumbs.
//
// MFMA 16x16x32_bf16 layouts (verified): A[m=l&15][k=(l>>4)*8+j] (k-contig);
// B frag f at Wf[f*512 + l*8 + j] = B[kb*32+(l>>4)*8+j][ct*16+(l&15)],
// f=ct*KB+kb; C/D col=l&15, row=(l>>4)*4+reg.

#define N_GRAPHS 64
#define N_CLASSES 10

typedef short bf8_t __attribute__((ext_vector_type(8)));
typedef float f4_t  __attribute__((ext_vector_type(4)));

__device__ __forceinline__ float b2f(unsigned int u) {
  return __uint_as_float(u << 16);
}
__device__ __forceinline__ unsigned short f2b(float f) {
  unsigned int x = __float_as_uint(f);
  x += 0x7fffu + ((x >> 16) & 1u);   // RNE (finite values only)
  return (unsigned short)(x >> 16);
}

// Per-block dtype detect; call with all 256 threads pre-divergence.
__device__ __forceinline__ void block_detect(const unsigned int* __restrict__ xraw,
    const unsigned int* __restrict__ eraw, int* f32, int* i64) {
  __shared__ int c_bf, c_nz;
  if (threadIdx.x == 0) { c_bf = 0; c_nz = 0; }
  __syncthreads();
  unsigned int d = xraw[threadIdx.x & 255];
  int e = (int)(((d & 0xffffu) >> 7) & 0xff);
  if (e >= 100 && e <= 140) atomicAdd(&c_bf, 1);
  if (eraw && threadIdx.x < 64 && eraw[2 * threadIdx.x + 1] != 0u) atomicAdd(&c_nz, 1);
  __syncthreads();
  *f32 = (c_bf < 150) ? 1 : 0;
  if (i64) *i64 = (c_nz == 0) ? 1 : 0;
}

struct WPtrs { const void* p[10]; };
static constexpr int WSEG[10] = {16384, 128, 8192, 64, 2048, 32, 512, 16, 160, 10};
static constexpr int WTOTAL   = 27546;
static constexpr int WOFF[10] = {0, 16384, 16512, 24704, 24768, 26816, 26848, 27360, 27376, 27536};

// Pure edge-degree atomics, 4 edges/thread (MLP without gather side effects).
__global__ __launch_bounds__(256) void edge_atomic_kernel(
    const unsigned int* __restrict__ xraw, const int* __restrict__ eraw,
    int* __restrict__ deg, int* __restrict__ rank, int E) {
  int f32, i64;
  block_detect(xraw, (const unsigned int*)eraw, &f32, &i64);
  #pragma unroll
  for (int r = 0; r < 4; ++r) {
    int e = blockIdx.x * 1024 + r * 256 + threadIdx.x;
    if (e < E) {
      int d = i64 ? eraw[2 * (E + e)] : eraw[E + e];
      rank[e] = atomicAdd(&deg[d], 1);
    }
  }
}

// [0,nb) scan (critical path) | [..XC) X->bf16 | [..BW) W canon | rest batch.
// Converts overlap the scan's mostly-idle machine.
__global__ __launch_bounds__(256) void scan_cvt_kernel(const int* __restrict__ deg,
    int* __restrict__ row_ptr, float* __restrict__ dinv,
    unsigned long long* __restrict__ desc, uint2* __restrict__ csr,
    const unsigned int* __restrict__ xraw, const int* __restrict__ eraw,
    WPtrs wp, unsigned short* __restrict__ wc,
    const int* __restrict__ braw, int* __restrict__ b32,
    unsigned short* __restrict__ xb,
    int nb, int XC, int BW, int n) {
  int f32, i64;
  block_detect(xraw, (const unsigned int*)eraw, &f32, &i64);
  const int bid = blockIdx.x;
  if (bid < nb) {
    __shared__ int ws[4];
    __shared__ int s_total;
    __shared__ unsigned int s_prev;
    const int b = bid, tid = threadIdx.x, lane = tid & 63, wv = tid >> 6;
    const int i = b * 256 + tid;
    int v = (i < n) ? (deg[i] + 1) : 0;      // +1: self-loop slot
    int x = v;
    #pragma unroll
    for (int off = 1; off < 64; off <<= 1) {
      int y = __shfl_up(x, off, 64);
      if (lane >= off) x += y;
    }
    if (lane == 63) ws[wv] = x;
    __syncthreads();
    int wbase = 0;
    for (int w = 0; w < wv; ++w) wbase += ws[w];
    int incl = x + wbase;
    if (tid == 0) {
      int tot = ws[0] + ws[1] + ws[2] + ws[3];
      s_total = tot;
      unsigned long long st = (b == 0) ? (2ULL << 62) : (1ULL << 62);
      atomicExch(&desc[b], st | (unsigned long long)(unsigned int)tot);
      if (b == 0) s_prev = 0u;
    }
    __syncthreads();
    if (b > 0 && wv == 0) {
      unsigned int running = 0;
      int j = b - 1;
      while (true) {
        int idx = j - lane;
        unsigned long long d;
        if (idx >= 0) {
          do { d = atomicAdd(&desc[idx], 0ULL); } while ((d >> 62) == 0ULL);
        } else {
          d = (2ULL << 62);
        }
        unsigned long long ball = __ballot((d >> 62) == 2ULL);
        int fp = ball ? (__ffsll((unsigned long long)ball) - 1) : 64;
        unsigned int contrib = (lane <= fp) ? (unsigned int)(d & 0xffffffffULL) : 0u;
        #pragma unroll
        for (int o = 32; o; o >>= 1) contrib += __shfl_xor(contrib, o, 64);
        running += contrib;
        if (fp < 64) break;
        j -= 64;
      }
      if (lane == 0) {
        atomicExch(&desc[b], (2ULL << 62) |
                   (unsigned long long)(unsigned int)(running + (unsigned int)s_total));
        s_prev = running;
      }
    }
    __syncthreads();
    int tot = (int)s_prev + incl;
    if (i < n) {
      row_ptr[i + 1] = tot;
      float di = rsqrtf((float)v);           // v = deg+1 (ref deg incl self)
      dinv[i] = di;
      uint2 se;
      se.x = (unsigned int)i;
      se.y = __float_as_uint(di * di);
      csr[tot - v] = se;                     // self-loop at row start
    }
    if (i == 0) row_ptr[0] = 0;
  } else if (bid < nb + XC) {
    int i = (bid - nb) * 2048 + threadIdx.x * 8;
    if (i < n * 128) {
      if (f32) {
        float4 u0 = *(const float4*)((const float*)xraw + i);
        float4 u1 = *(const float4*)((const float*)xraw + i + 4);
        uint4 o;
        o.x = (unsigned int)f2b(u0.x) | ((unsigned int)f2b(u0.y) << 16);
        o.y = (unsigned int)f2b(u0.z) | ((unsigned int)f2b(u0.w) << 16);
        o.z = (unsigned int)f2b(u1.x) | ((unsigned int)f2b(u1.y) << 16);
        o.w = (unsigned int)f2b(u1.z) | ((unsigned int)f2b(u1.w) << 16);
        *(uint4*)&xb[i] = o;
      } else {
        *(uint4*)&xb[i] = *(const uint4*)((const unsigned short*)xraw + i);
      }
    }
  } else if (bid < nb + XC + BW) {
    int i = (bid - nb - XC) * 256 + threadIdx.x;
    if (i >= WTOTAL) return;
    int off = i, s = 0;
    #pragma unroll
    for (int t = 0; t < 10; ++t) {
      if (s == 0 && off >= WSEG[t]) { off -= WSEG[t]; } else if (s == 0) { s = t + 1; }
    }
    s -= 1;
    int soff = off;
    if ((s & 1) == 0 && s <= 6) {           // W1..W4 -> fragment-major
      int KB, FOUT;
      if (s == 0)      { KB = 4; FOUT = 128; }
      else if (s == 2) { KB = 4; FOUT = 64; }
      else if (s == 4) { KB = 2; FOUT = 32; }
      else             { KB = 1; FOUT = 16; }
      int j = off & 7, l = (off >> 3) & 63, f = off >> 9;
      int ct = f / KB, kb = f - ct * KB;
      int k = kb * 32 + ((l >> 4) << 3) + j;
      int nn = ct * 16 + (l & 15);
      soff = k * FOUT + nn;
    }
    const void* p = wp.p[s];
    wc[WOFF[s] + off] = f32 ? f2b(((const float*)p)[soff])
                            : ((const unsigned short*)p)[soff];
  } else {
    int i = (bid - nb - XC - BW) * 256 + threadIdx.x;
    if (i < n) b32[i] = i64 ? braw[2 * i] : braw[i];
  }
}

// Atomic-free CSR fill: pos = row_ptr[dst] + 1 + rank[e] (slot 0 = self).
__global__ __launch_bounds__(256) void fill_kernel(
    const int* __restrict__ eraw, const unsigned int* __restrict__ xraw,
    const int* __restrict__ row_ptr, const int* __restrict__ rank,
    const float* __restrict__ dinv, uint2* __restrict__ csr, int E) {
  int f32, i64;
  block_detect(xraw, (const unsigned int*)eraw, &f32, &i64);
  int e = blockIdx.x * 256 + threadIdx.x;
  if (e >= E) return;
  int s, d;
  if (i64) { s = eraw[2 * e]; d = eraw[2 * (E + e)]; }
  else     { s = eraw[e];     d = eraw[E + e]; }
  int pos = row_ptr[d] + 1 + rank[e];
  uint2 v;
  v.x = (unsigned int)s;
  v.y = __float_as_uint(dinv[s] * dinv[d]);
  csr[pos] = v;
}

// ---- generic per-lane vector of DW dwords ----
template<int DW> struct UVec { unsigned int d[DW]; };
template<int DW>
__device__ __forceinline__ UVec<DW> uload(const unsigned int* p) {
  UVec<DW> r;
  if constexpr (DW == 4) { uint4 v = *(const uint4*)p; r.d[0]=v.x; r.d[1]=v.y; r.d[2]=v.z; r.d[3]=v.w; }
  else if constexpr (DW == 2) { uint2 v = *(const uint2*)p; r.d[0]=v.x; r.d[1]=v.y; }
  else { r.d[0] = *p; }
  return r;
}
template<int DW>
__device__ __forceinline__ void ustore(unsigned int* p, const UVec<DW>& v) {
  if constexpr (DW == 4) { *(uint4*)p = make_uint4(v.d[0], v.d[1], v.d[2], v.d[3]); }
  else if constexpr (DW == 2) { *(uint2*)p = make_uint2(v.d[0], v.d[1]); }
  else { *p = v.d[0]; }
}

// R16's proven gather: shfl-broadcast csr + 4-deep pipelined row loads.
template<int DW, int LPG>
__device__ __forceinline__ void gather_shfl(
    const unsigned int* __restrict__ H2, int FPD,
    const uint2* __restrict__ csr, int e0, int e1, int l, float* a) {
  for (int base = e0; base < e1; base += LPG) {
    int cnt = e1 - base < LPG ? e1 - base : LPG;
    uint2 my = csr[(base + l < e1) ? (base + l) : (e1 - 1)];
    for (int j0 = 0; j0 < cnt; j0 += 4) {
      int   sj[4];
      float cj[4];
      #pragma unroll
      for (int jj = 0; jj < 4; ++jj) {
        int j = j0 + jj;
        sj[jj] = __shfl((int)my.x, j & (LPG - 1), LPG);
        float cc = __uint_as_float(__shfl((int)my.y, j & (LPG - 1), LPG));
        cj[jj] = (j < cnt) ? cc : 0.f;
      }
      UVec<DW> v[4];
      #pragma unroll
      for (int jj = 0; jj < 4; ++jj)
        v[jj] = uload<DW>(H2 + (size_t)sj[jj] * FPD + l * DW);
      #pragma unroll
      for (int jj = 0; jj < 4; ++jj) {
        #pragma unroll
        for (int d = 0; d < DW; ++d) {
          a[2*d]   = fmaf(b2f(v[jj].d[d] & 0xffffu), cj[jj], a[2*d]);
          a[2*d+1] = fmaf(b2f(v[jj].d[d] >> 16),     cj[jj], a[2*d+1]);
        }
      }
    }
  }
}

// Layer 1 fused: agg(Xbf16) -> @W1 -> +b1,relu -> @W2 -> Z2 (64 feats).
__global__ __launch_bounds__(256) void aggemm0_kernel(
    const unsigned short* __restrict__ Xb,
    const int* __restrict__ row_ptr, const uint2* __restrict__ csr,
    const unsigned short* __restrict__ wc,   // canonical buffer (W1,b1,W2)
    unsigned short* __restrict__ Hout, int n) {
  constexpr int LPG = 16, DW = 4, LD = 136;
  __shared__ unsigned short T[16 * LD];
  __shared__ unsigned short T2[16 * LD];
  const int r = threadIdx.x / LPG, l = threadIdx.x % LPG;
  const int node0 = blockIdx.x * 16;
  const int g = node0 + r;
  UVec<DW> o;
  #pragma unroll
  for (int d = 0; d < DW; ++d) o.d[d] = 0u;
  if (g < n) {
    float a[2 * DW];
    #pragma unroll
    for (int d = 0; d < 2 * DW; ++d) a[d] = 0.f;
    gather_shfl<DW, LPG>((const unsigned int*)Xb, 64, csr,
                         row_ptr[g], row_ptr[g + 1], l, a);
    #pragma unroll
    for (int d = 0; d < DW; ++d)
      o.d[d] = (unsigned int)f2b(a[2*d]) | ((unsigned int)f2b(a[2*d+1]) << 16);
  }
  ustore<DW>((unsigned int*)&T[r * LD + l * DW * 2], o);
  __syncthreads();
  const int w = threadIdx.x >> 6;
  const int ll = threadIdx.x & 63;
  const int l15 = ll & 15, quad = ll >> 4;
  const unsigned short* W1f = wc + WOFF[0];
  const unsigned short* b1  = wc + WOFF[1];
  const unsigned short* W2f = wc + WOFF[2];
  // MFMA stage 1: wave w covers ct1 = 2w, 2w+1 (128-out)
  #pragma unroll
  for (int c = 0; c < 2; ++c) {
    const int ct1 = w * 2 + c;
    f4_t acc = {0.f, 0.f, 0.f, 0.f};
    #pragma unroll
    for (int kb = 0; kb < 4; ++kb) {
      bf8_t afr = *(const bf8_t*)&T[l15 * LD + kb * 32 + quad * 8];
      bf8_t bfr = *(const bf8_t*)&W1f[((ct1 * 4 + kb) * 64 + ll) * 8];
      acc = __builtin_amdgcn_mfma_f32_16x16x32_bf16(afr, bfr, acc, 0, 0, 0);
    }
    float bv = b2f(b1[ct1 * 16 + l15]);
    #pragma unroll
    for (int rr = 0; rr < 4; ++rr)
      T2[(quad * 4 + rr) * LD + ct1 * 16 + l15] = f2b(fmaxf(acc[rr] + bv, 0.f));
  }
  __syncthreads();
  // MFMA stage 2: wave w covers ct2 = w (64-out)
  f4_t a2 = {0.f, 0.f, 0.f, 0.f};
  #pragma unroll
  for (int kb = 0; kb < 4; ++kb) {
    bf8_t afr = *(const bf8_t*)&T2[l15 * LD + kb * 32 + quad * 8];
    bf8_t bfr = *(const bf8_t*)&W2f[((w * 4 + kb) * 64 + ll) * 8];
    a2 = __builtin_amdgcn_mfma_f32_16x16x32_bf16(afr, bfr, a2, 0, 0, 0);
  }
  #pragma unroll
  for (int rr = 0; rr < 4; ++rr) {
    int node = node0 + quad * 4 + rr;
    if (node < n)
      Hout[(size_t)node * 64 + w * 16 + l15] = f2b(a2[rr]);
  }
}

// Fused agg(FIN, bias, relu) -> LDS tile -> MFMA @ Wf(FIN x FOUT) -> Hout.
// Self-loop from CSR slot 0. 4-deep shfl gather (R16-proven).
template<int FIN, int FOUT, int LPG>
__global__ __launch_bounds__(256) void aggemm_kernel(
    const unsigned short* __restrict__ Hin,
    const int* __restrict__ row_ptr, const uint2* __restrict__ csr,
    const unsigned short* __restrict__ bias,
    const unsigned short* __restrict__ Wf, unsigned short* __restrict__ Hout, int n) {
  constexpr int DW  = FIN / LPG / 2;
  constexpr int NPB = 256 / LPG;
  constexpr int LD  = FIN + 8;
  constexpr int KB  = FIN / 32;
  constexpr int CT  = FOUT / 16;
  constexpr int MT  = NPB / 16;
  __shared__ unsigned short T[NPB * LD];
  const int r = threadIdx.x / LPG, l = threadIdx.x % LPG;
  const int node0 = blockIdx.x * NPB;
  const int g = node0 + r;
  UVec<DW> o;
  #pragma unroll
  for (int d = 0; d < DW; ++d) o.d[d] = 0u;
  if (g < n) {
    float a[2 * DW];
    #pragma unroll
    for (int d = 0; d < 2 * DW; ++d) a[d] = 0.f;
    gather_shfl<DW, LPG>((const unsigned int*)Hin, FIN / 2, csr,
                         row_ptr[g], row_ptr[g + 1], l, a);
    UVec<DW> bb = uload<DW>((const unsigned int*)bias + l * DW);
    #pragma unroll
    for (int d = 0; d < DW; ++d) {
      float lo = fmaxf(a[2*d]   + b2f(bb.d[d] & 0xffffu), 0.f);
      float hi = fmaxf(a[2*d+1] + b2f(bb.d[d] >> 16), 0.f);
      o.d[d] = (unsigned int)f2b(lo) | ((unsigned int)f2b(hi) << 16);
    }
  }
  ustore<DW>((unsigned int*)&T[r * LD + l * DW * 2], o);
  __syncthreads();
  const int w = threadIdx.x >> 6;
  if (w < MT * CT && node0 < n) {
    const int mt = w / CT, ct = w % CT;
    const int ll = threadIdx.x & 63;
    const int r16 = ll & 15, quad = ll >> 4;
    bf8_t afrag[KB], bfrag[KB];
    #pragma unroll
    for (int kb = 0; kb < KB; ++kb) {
      afrag[kb] = *(const bf8_t*)(&T[(mt * 16 + r16) * LD + quad * 8 + kb * 32]);
      bfrag[kb] = *(const bf8_t*)(Wf + ((ct * KB + kb) * 64 + ll) * 8);
    }
    f4_t acc = {0.f, 0.f, 0.f, 0.f};
    #pragma unroll
    for (int kb = 0; kb < KB; ++kb)
      acc = __builtin_amdgcn_mfma_f32_16x16x32_bf16(afrag[kb], bfrag[kb], acc, 0, 0, 0);
    #pragma unroll
    for (int rr = 0; rr < 4; ++rr) {
      int node = node0 + mt * 16 + quad * 4 + rr;
      if (node < n)
        Hout[(size_t)node * FOUT + ct * 16 + r16] = f2b(acc[rr]);
    }
  }
}

// Fused last-layer agg + mean-pool. Full 8-deep direct gather (R16-proven).
__global__ __launch_bounds__(256) void agg_pool_kernel(
    const unsigned short* __restrict__ Hin,
    const int* __restrict__ row_ptr, const uint2* __restrict__ csr,
    const unsigned short* __restrict__ bias,
    const int* __restrict__ batch, float* __restrict__ pooled,
    float* __restrict__ cnt, int n) {
  __shared__ float acc[N_GRAPHS * 16];
  __shared__ float ccnt[N_GRAPHS];
  for (int i = threadIdx.x; i < N_GRAPHS * 16; i += 256) acc[i] = 0.f;
  if (threadIdx.x < N_GRAPHS) ccnt[threadIdx.x] = 0.f;
  __syncthreads();
  const int r = threadIdx.x >> 3, l = threadIdx.x & 7;
  const int g = blockIdx.x * 32 + r;
  if (g < n) {
    const unsigned int* H2 = (const unsigned int*)Hin;
    float a0 = 0.f, a1 = 0.f;
    const int e0 = row_ptr[g], e1 = row_ptr[g + 1];
    for (int base = e0; base < e1; base += 8) {
      uint2 eb[8];
      #pragma unroll
      for (int j = 0; j < 8; ++j)
        eb[j] = csr[(base + j < e1) ? (base + j) : (e1 - 1)];
      float cj[8];
      unsigned int v[8];
      #pragma unroll
      for (int j = 0; j < 8; ++j)
        cj[j] = (base + j < e1) ? __uint_as_float(eb[j].y) : 0.f;
      #pragma unroll
      for (int j = 0; j < 8; ++j)
        v[j] = H2[(size_t)eb[j].x * 8 + l];
      #pragma unroll
      for (int j = 0; j < 8; ++j) {
        a0 = fmaf(b2f(v[j] & 0xffffu), cj[j], a0);
        a1 = fmaf(b2f(v[j] >> 16),     cj[j], a1);
      }
    }
    unsigned int bb = ((const unsigned int*)bias)[l];
    a0 = fmaxf(a0 + b2f(bb & 0xffffu), 0.f);
    a1 = fmaxf(a1 + b2f(bb >> 16), 0.f);
    int gb = batch[g];
    atomicAdd(&acc[gb * 16 + l * 2 + 0], a0);
    atomicAdd(&acc[gb * 16 + l * 2 + 1], a1);
    if (l == 0) atomicAdd(&ccnt[gb], 1.f);
  }
  __syncthreads();
  for (int i = threadIdx.x; i < N_GRAPHS * 16; i += 256)
    if (acc[i] != 0.f) atomicAdd(&pooled[i], acc[i]);
  if (threadIdx.x < N_GRAPHS && ccnt[threadIdx.x] != 0.f)
    atomicAdd(&cnt[threadIdx.x], ccnt[threadIdx.x]);
}

__global__ __launch_bounds__(256) void final_kernel(const float* __restrict__ pooled,
    const float* __restrict__ cnt, const unsigned short* __restrict__ wc,
    void* __restrict__ out, const unsigned int* __restrict__ xraw) {
  int f32;
  block_detect(xraw, nullptr, &f32, nullptr);
  int id = blockIdx.x * 256 + threadIdx.x;
  if (id >= N_GRAPHS * N_CLASSES) return;
  const unsigned short* Wlin = wc + WOFF[8];
  const unsigned short* blin = wc + WOFF[9];
  int g = id / N_CLASSES, c = id - g * N_CLASSES;
  float inv = 1.0f / fmaxf(cnt[g], 1.0f);
  float a = b2f(blin[c]);
  #pragma unroll
  for (int f = 0; f < 16; ++f)
    a = fmaf(pooled[g * 16 + f] * inv, b2f(Wlin[f * N_CLASSES + c]), a);
  if (f32) ((float*)out)[id] = a;
  else     ((unsigned short*)out)[id] = f2b(a);
}

extern "C" void kernel_launch(void* const* d_in, const int* in_sizes, int n_in,
                              void* d_out, int out_size, void* d_ws, size_t ws_size,
                              hipStream_t stream) {
  const unsigned int* xraw = (const unsigned int*)d_in[0];
  const int* eraw          = (const int*)d_in[1];
  const int* braw          = (const int*)d_in[2];

  const int N = in_sizes[2];
  const int E = in_sizes[1] / 2;
  const int nb = (N + 255) / 256;

  char* p = (char*)d_ws;
  auto alloc = [&](size_t bytes) -> void* {
    void* r = (void*)p;
    p += (bytes + 255) & ~(size_t)255;
    return r;
  };
  // zero region: deg | desc | pooled | cnt  (single memset)
  const size_t off_desc = ((size_t)N * 4 + 255) & ~(size_t)255;
  const size_t off_pool = (off_desc + (size_t)nb * 8 + 255) & ~(size_t)255;
  const size_t ztotal   = off_pool + (N_GRAPHS * 16 + N_GRAPHS) * 4;
  char* zbase = (char*)alloc(ztotal);
  int*   deg    = (int*)zbase;
  unsigned long long* desc = (unsigned long long*)(zbase + off_desc);
  float* pooled = (float*)(zbase + off_pool);
  float* cntf   = pooled + N_GRAPHS * 16;

  int*   row_ptr  = (int*)  alloc((size_t)(N + 1) * 4);
  int*   rank     = (int*)  alloc((size_t)E * 4);
  float* dinv     = (float*)alloc((size_t)N * 4);
  int*   batch32  = (int*)  alloc((size_t)N * 4);
  uint2* csr      = (uint2*)alloc((size_t)(E + N + 16) * 8);
  unsigned short* wcan  = (unsigned short*)alloc((size_t)WTOTAL * 2);
  unsigned short* xb    = (unsigned short*)alloc((size_t)N * 128 * 2);
  unsigned short* hbufA = (unsigned short*)alloc((size_t)N * 128 * 2);
  unsigned short* hbufB = (unsigned short*)alloc((size_t)N * 128 * 2);

  hipMemsetAsync(zbase, 0, ztotal, stream);

  WPtrs wp;
  for (int i = 0; i < 10; ++i) wp.p[i] = d_in[3 + i];

  const int BW  = (WTOTAL + 255) / 256;
  const int BB  = nb;
  const int BE  = (E + 255) / 256;
  const int BE4 = (E + 1023) / 1024;
  const int XC  = (N * 128 + 2047) / 2048;

  edge_atomic_kernel<<<BE4, 256, 0, stream>>>(xraw, eraw, deg, rank, E);

  scan_cvt_kernel<<<nb + XC + BW + BB, 256, 0, stream>>>(deg, row_ptr, dinv,
      desc, csr, xraw, eraw, wp, wcan, braw, batch32, xb, nb, XC, BW, N);

  const unsigned short* b2 = wcan + WOFF[3];
  const unsigned short* W3 = wcan + WOFF[4];
  const unsigned short* b3 = wcan + WOFF[5];
  const unsigned short* W4 = wcan + WOFF[6];
  const unsigned short* b4 = wcan + WOFF[7];

  fill_kernel<<<BE, 256, 0, stream>>>(eraw, xraw, row_ptr, rank, dinv, csr, E);

  aggemm0_kernel<<<(N + 15) / 16, 256, 0, stream>>>(
      xb, row_ptr, csr, wcan, hbufB, N);
  aggemm_kernel<64, 32, 8><<<(N + 31) / 32, 256, 0, stream>>>(
      hbufB, row_ptr, csr, b2, W3, hbufA, N);
  aggemm_kernel<32, 16, 8><<<(N + 31) / 32, 256, 0, stream>>>(
      hbufA, row_ptr, csr, b3, W4, hbufB, N);
  agg_pool_kernel<<<(N + 31) / 32, 256, 0, stream>>>(hbufB, row_ptr, csr, b4,
      batch32, pooled, cntf, N);

  final_kernel<<<(N_GRAPHS * N_CLASSES + 255) / 256, 256, 0, stream>>>(pooled, cntf, wcan, d_out, xraw);
}

// Round 10
// 207.792 us; speedup vs baseline: 1.0240x; 1.0240x over previous
//
#include <hip/hip_runtime.h>
#include <hip/hip_bf16.h>

// GCN forward, MI355X. Round 19: REVERT to R16 (measured best, 207.98us).
// R17 (8-deep reg-broadcast) and R18 (scan+cvt merge) both regressed; the
// configuration space around this structure is locally flat-to-worse in
// every probed direction. This is the converged kernel.
//   memset(deg|desc|pooled|cnt)
//   cvtwe      : ONE dispatch: [0,BE2) degree atomics (lead), 2 edges/thread,
//                return -> rank[e] | [..XC) X->bf16 (hides under atomics) |
//                [..BW) W canon | [..BB) batch
//   scan       : decoupled lookback over (deg+1); writes self-loop CSR slot
//   fill       : atomic-free scatter  pos = row_ptr[dst] + 1 + rank[e]
//   aggemm0    : agg(Xbf16) 4-deep shfl gather -> @W1 -> +b1,relu -> @W2
//   aggemm x2  : 4-deep shfl gather + LDS tile + MFMA @Wnext
//   agg_pool   : 8-deep direct gather + LDS pool -> atomics
//   final      : 64x16 @ 16x10 linear
//
// Lessons: R5 fuse at AGG grid; R7 no wide-grid threadfence; R10 capture
// degree atomicAdd return as rank; R11 atomic limiter is latency*concurrency;
// R12/R14 staging flavors don't matter, the gather does; R13 don't bet on
// unverified HW mappings; R15 agg chain is LOAD-LATENCY-bound (4-deep
// pipelining +18us; depth>4 costs occupancy, R17); R16 gemm1 elimination
// traffic-neutral but -1 dispatch; R18 converts must overlap the ATOMIC
// phase, not the scan. Floor: 600k random RMW atomics + ~2.4M random 32B
// row gathers — irreducible without an algorithm change.
//
// MFMA 16x16x32_bf16 layouts (verified): A[m=l&15][k=(l>>4)*8+j] (k-contig);
// B frag f at Wf[f*512 + l*8 + j] = B[kb*32+(l>>4)*8+j][ct*16+(l&15)],
// f=ct*KB+kb; C/D col=l&15, row=(l>>4)*4+reg.

#define N_GRAPHS 64
#define N_CLASSES 10

typedef short bf8_t __attribute__((ext_vector_type(8)));
typedef float f4_t  __attribute__((ext_vector_type(4)));

__device__ __forceinline__ float b2f(unsigned int u) {
  return __uint_as_float(u << 16);
}
__device__ __forceinline__ unsigned short f2b(float f) {
  unsigned int x = __float_as_uint(f);
  x += 0x7fffu + ((x >> 16) & 1u);   // RNE (finite values only)
  return (unsigned short)(x >> 16);
}

// Per-block dtype detect; call with all 256 threads pre-divergence.
__device__ __forceinline__ void block_detect(const unsigned int* __restrict__ xraw,
    const unsigned int* __restrict__ eraw, int* f32, int* i64) {
  __shared__ int c_bf, c_nz;
  if (threadIdx.x == 0) { c_bf = 0; c_nz = 0; }
  __syncthreads();
  unsigned int d = xraw[threadIdx.x & 255];
  int e = (int)(((d & 0xffffu) >> 7) & 0xff);
  if (e >= 100 && e <= 140) atomicAdd(&c_bf, 1);
  if (eraw && threadIdx.x < 64 && eraw[2 * threadIdx.x + 1] != 0u) atomicAdd(&c_nz, 1);
  __syncthreads();
  *f32 = (c_bf < 150) ? 1 : 0;
  if (i64) *i64 = (c_nz == 0) ? 1 : 0;
}

struct WPtrs { const void* p[10]; };
static constexpr int WSEG[10] = {16384, 128, 8192, 64, 2048, 32, 512, 16, 160, 10};
static constexpr int WTOTAL   = 27546;
static constexpr int WOFF[10] = {0, 16384, 16512, 24704, 24768, 26816, 26848, 27360, 27376, 27536};

// [0,BE2) atomics | [..+XC) X->bf16 | [..+BW) weights | rest batch.
__global__ __launch_bounds__(256) void cvtwe_kernel(
    const unsigned int* __restrict__ xraw, WPtrs wp, unsigned short* __restrict__ wc,
    const int* __restrict__ braw, int* __restrict__ b32,
    const int* __restrict__ eraw, int* __restrict__ deg, int* __restrict__ rank,
    unsigned short* __restrict__ xb,
    int BE2, int XC, int BW, int n, int E) {
  int f32, i64;
  block_detect(xraw, (const unsigned int*)eraw, &f32, &i64);
  const int bid = blockIdx.x;
  if (bid < BE2) {
    #pragma unroll
    for (int r = 0; r < 2; ++r) {
      int e = bid * 512 + r * 256 + threadIdx.x;
      if (e < E) {
        int d = i64 ? eraw[2 * (E + e)] : eraw[E + e];
        rank[e] = atomicAdd(&deg[d], 1);
      }
    }
  } else if (bid < BE2 + XC) {
    int i = (bid - BE2) * 2048 + threadIdx.x * 8;
    if (i < n * 128) {
      if (f32) {
        float4 u0 = *(const float4*)((const float*)xraw + i);
        float4 u1 = *(const float4*)((const float*)xraw + i + 4);
        uint4 o;
        o.x = (unsigned int)f2b(u0.x) | ((unsigned int)f2b(u0.y) << 16);
        o.y = (unsigned int)f2b(u0.z) | ((unsigned int)f2b(u0.w) << 16);
        o.z = (unsigned int)f2b(u1.x) | ((unsigned int)f2b(u1.y) << 16);
        o.w = (unsigned int)f2b(u1.z) | ((unsigned int)f2b(u1.w) << 16);
        *(uint4*)&xb[i] = o;
      } else {
        *(uint4*)&xb[i] = *(const uint4*)((const unsigned short*)xraw + i);
      }
    }
  } else if (bid < BE2 + XC + BW) {
    int i = (bid - BE2 - XC) * 256 + threadIdx.x;
    if (i >= WTOTAL) return;
    int off = i, s = 0;
    #pragma unroll
    for (int t = 0; t < 10; ++t) {
      if (s == 0 && off >= WSEG[t]) { off -= WSEG[t]; } else if (s == 0) { s = t + 1; }
    }
    s -= 1;
    int soff = off;
    if ((s & 1) == 0 && s <= 6) {           // W1..W4 -> fragment-major
      int KB, FOUT;
      if (s == 0)      { KB = 4; FOUT = 128; }
      else if (s == 2) { KB = 4; FOUT = 64; }
      else if (s == 4) { KB = 2; FOUT = 32; }
      else             { KB = 1; FOUT = 16; }
      int j = off & 7, l = (off >> 3) & 63, f = off >> 9;
      int ct = f / KB, kb = f - ct * KB;
      int k = kb * 32 + ((l >> 4) << 3) + j;
      int nn = ct * 16 + (l & 15);
      soff = k * FOUT + nn;
    }
    const void* p = wp.p[s];
    wc[WOFF[s] + off] = f32 ? f2b(((const float*)p)[soff])
                            : ((const unsigned short*)p)[soff];
  } else {
    int i = (bid - BE2 - XC - BW) * 256 + threadIdx.x;
    if (i < n) b32[i] = i64 ? braw[2 * i] : braw[i];
  }
}

// Scan over (deg+1) with decoupled lookback; writes self-loop CSR slots.
__global__ __launch_bounds__(256) void scan_kernel(const int* __restrict__ deg,
    int* __restrict__ row_ptr, float* __restrict__ dinv,
    unsigned long long* __restrict__ desc, uint2* __restrict__ csr, int n) {
  __shared__ int ws[4];
  __shared__ int s_total;
  __shared__ unsigned int s_prev;
  const int b = blockIdx.x, tid = threadIdx.x, lane = tid & 63, wv = tid >> 6;
  const int i = b * 256 + tid;
  int v = (i < n) ? (deg[i] + 1) : 0;      // +1: self-loop slot
  int x = v;
  #pragma unroll
  for (int off = 1; off < 64; off <<= 1) {
    int y = __shfl_up(x, off, 64);
    if (lane >= off) x += y;
  }
  if (lane == 63) ws[wv] = x;
  __syncthreads();
  int wbase = 0;
  for (int w = 0; w < wv; ++w) wbase += ws[w];
  int incl = x + wbase;
  if (tid == 0) {
    int tot = ws[0] + ws[1] + ws[2] + ws[3];
    s_total = tot;
    unsigned long long st = (b == 0) ? (2ULL << 62) : (1ULL << 62);
    atomicExch(&desc[b], st | (unsigned long long)(unsigned int)tot);
    if (b == 0) s_prev = 0u;
  }
  __syncthreads();
  if (b > 0 && wv == 0) {
    unsigned int running = 0;
    int j = b - 1;
    while (true) {
      int idx = j - lane;
      unsigned long long d;
      if (idx >= 0) {
        do { d = atomicAdd(&desc[idx], 0ULL); } while ((d >> 62) == 0ULL);
      } else {
        d = (2ULL << 62);
      }
      unsigned long long ball = __ballot((d >> 62) == 2ULL);
      int fp = ball ? (__ffsll((unsigned long long)ball) - 1) : 64;
      unsigned int contrib = (lane <= fp) ? (unsigned int)(d & 0xffffffffULL) : 0u;
      #pragma unroll
      for (int o = 32; o; o >>= 1) contrib += __shfl_xor(contrib, o, 64);
      running += contrib;
      if (fp < 64) break;
      j -= 64;
    }
    if (lane == 0) {
      atomicExch(&desc[b], (2ULL << 62) |
                 (unsigned long long)(unsigned int)(running + (unsigned int)s_total));
      s_prev = running;
    }
  }
  __syncthreads();
  int tot = (int)s_prev + incl;
  if (i < n) {
    row_ptr[i + 1] = tot;
    float di = rsqrtf((float)v);           // v = deg+1 (ref deg incl self)
    dinv[i] = di;
    uint2 se;
    se.x = (unsigned int)i;
    se.y = __float_as_uint(di * di);
    csr[tot - v] = se;                     // self-loop at row start
  }
  if (i == 0) row_ptr[0] = 0;
}

// Atomic-free CSR fill: pos = row_ptr[dst] + 1 + rank[e] (slot 0 = self).
__global__ __launch_bounds__(256) void fill_kernel(
    const int* __restrict__ eraw, const unsigned int* __restrict__ xraw,
    const int* __restrict__ row_ptr, const int* __restrict__ rank,
    const float* __restrict__ dinv, uint2* __restrict__ csr, int E) {
  int f32, i64;
  block_detect(xraw, (const unsigned int*)eraw, &f32, &i64);
  int e = blockIdx.x * 256 + threadIdx.x;
  if (e >= E) return;
  int s, d;
  if (i64) { s = eraw[2 * e]; d = eraw[2 * (E + e)]; }
  else     { s = eraw[e];     d = eraw[E + e]; }
  int pos = row_ptr[d] + 1 + rank[e];
  uint2 v;
  v.x = (unsigned int)s;
  v.y = __float_as_uint(dinv[s] * dinv[d]);
  csr[pos] = v;
}

// ---- generic per-lane vector of DW dwords ----
template<int DW> struct UVec { unsigned int d[DW]; };
template<int DW>
__device__ __forceinline__ UVec<DW> uload(const unsigned int* p) {
  UVec<DW> r;
  if constexpr (DW == 4) { uint4 v = *(const uint4*)p; r.d[0]=v.x; r.d[1]=v.y; r.d[2]=v.z; r.d[3]=v.w; }
  else if constexpr (DW == 2) { uint2 v = *(const uint2*)p; r.d[0]=v.x; r.d[1]=v.y; }
  else { r.d[0] = *p; }
  return r;
}
template<int DW>
__device__ __forceinline__ void ustore(unsigned int* p, const UVec<DW>& v) {
  if constexpr (DW == 4) { *(uint4*)p = make_uint4(v.d[0], v.d[1], v.d[2], v.d[3]); }
  else if constexpr (DW == 2) { *(uint2*)p = make_uint2(v.d[0], v.d[1]); }
  else { *p = v.d[0]; }
}

// R16's proven gather: shfl-broadcast csr + 4-deep pipelined row loads.
template<int DW, int LPG>
__device__ __forceinline__ void gather_shfl(
    const unsigned int* __restrict__ H2, int FPD,
    const uint2* __restrict__ csr, int e0, int e1, int l, float* a) {
  for (int base = e0; base < e1; base += LPG) {
    int cnt = e1 - base < LPG ? e1 - base : LPG;
    uint2 my = csr[(base + l < e1) ? (base + l) : (e1 - 1)];
    for (int j0 = 0; j0 < cnt; j0 += 4) {
      int   sj[4];
      float cj[4];
      #pragma unroll
      for (int jj = 0; jj < 4; ++jj) {
        int j = j0 + jj;
        sj[jj] = __shfl((int)my.x, j & (LPG - 1), LPG);
        float cc = __uint_as_float(__shfl((int)my.y, j & (LPG - 1), LPG));
        cj[jj] = (j < cnt) ? cc : 0.f;
      }
      UVec<DW> v[4];
      #pragma unroll
      for (int jj = 0; jj < 4; ++jj)
        v[jj] = uload<DW>(H2 + (size_t)sj[jj] * FPD + l * DW);
      #pragma unroll
      for (int jj = 0; jj < 4; ++jj) {
        #pragma unroll
        for (int d = 0; d < DW; ++d) {
          a[2*d]   = fmaf(b2f(v[jj].d[d] & 0xffffu), cj[jj], a[2*d]);
          a[2*d+1] = fmaf(b2f(v[jj].d[d] >> 16),     cj[jj], a[2*d+1]);
        }
      }
    }
  }
}

// Layer 1 fused: agg(Xbf16) -> @W1 -> +b1,relu -> @W2 -> Z2 (64 feats).
__global__ __launch_bounds__(256) void aggemm0_kernel(
    const unsigned short* __restrict__ Xb,
    const int* __restrict__ row_ptr, const uint2* __restrict__ csr,
    const unsigned short* __restrict__ wc,   // canonical buffer (W1,b1,W2)
    unsigned short* __restrict__ Hout, int n) {
  constexpr int LPG = 16, DW = 4, LD = 136;
  __shared__ unsigned short T[16 * LD];
  __shared__ unsigned short T2[16 * LD];
  const int r = threadIdx.x / LPG, l = threadIdx.x % LPG;
  const int node0 = blockIdx.x * 16;
  const int g = node0 + r;
  UVec<DW> o;
  #pragma unroll
  for (int d = 0; d < DW; ++d) o.d[d] = 0u;
  if (g < n) {
    float a[2 * DW];
    #pragma unroll
    for (int d = 0; d < 2 * DW; ++d) a[d] = 0.f;
    gather_shfl<DW, LPG>((const unsigned int*)Xb, 64, csr,
                         row_ptr[g], row_ptr[g + 1], l, a);
    #pragma unroll
    for (int d = 0; d < DW; ++d)
      o.d[d] = (unsigned int)f2b(a[2*d]) | ((unsigned int)f2b(a[2*d+1]) << 16);
  }
  ustore<DW>((unsigned int*)&T[r * LD + l * DW * 2], o);
  __syncthreads();
  const int w = threadIdx.x >> 6;
  const int ll = threadIdx.x & 63;
  const int l15 = ll & 15, quad = ll >> 4;
  const unsigned short* W1f = wc + WOFF[0];
  const unsigned short* b1  = wc + WOFF[1];
  const unsigned short* W2f = wc + WOFF[2];
  // MFMA stage 1: wave w covers ct1 = 2w, 2w+1 (128-out)
  #pragma unroll
  for (int c = 0; c < 2; ++c) {
    const int ct1 = w * 2 + c;
    f4_t acc = {0.f, 0.f, 0.f, 0.f};
    #pragma unroll
    for (int kb = 0; kb < 4; ++kb) {
      bf8_t afr = *(const bf8_t*)&T[l15 * LD + kb * 32 + quad * 8];
      bf8_t bfr = *(const bf8_t*)&W1f[((ct1 * 4 + kb) * 64 + ll) * 8];
      acc = __builtin_amdgcn_mfma_f32_16x16x32_bf16(afr, bfr, acc, 0, 0, 0);
    }
    float bv = b2f(b1[ct1 * 16 + l15]);
    #pragma unroll
    for (int rr = 0; rr < 4; ++rr)
      T2[(quad * 4 + rr) * LD + ct1 * 16 + l15] = f2b(fmaxf(acc[rr] + bv, 0.f));
  }
  __syncthreads();
  // MFMA stage 2: wave w covers ct2 = w (64-out)
  f4_t a2 = {0.f, 0.f, 0.f, 0.f};
  #pragma unroll
  for (int kb = 0; kb < 4; ++kb) {
    bf8_t afr = *(const bf8_t*)&T2[l15 * LD + kb * 32 + quad * 8];
    bf8_t bfr = *(const bf8_t*)&W2f[((w * 4 + kb) * 64 + ll) * 8];
    a2 = __builtin_amdgcn_mfma_f32_16x16x32_bf16(afr, bfr, a2, 0, 0, 0);
  }
  #pragma unroll
  for (int rr = 0; rr < 4; ++rr) {
    int node = node0 + quad * 4 + rr;
    if (node < n)
      Hout[(size_t)node * 64 + w * 16 + l15] = f2b(a2[rr]);
  }
}

// Fused agg(FIN, bias, relu) -> LDS tile -> MFMA @ Wf(FIN x FOUT) -> Hout.
// Self-loop from CSR slot 0. 4-deep shfl gather (R16-proven).
template<int FIN, int FOUT, int LPG>
__global__ __launch_bounds__(256) void aggemm_kernel(
    const unsigned short* __restrict__ Hin,
    const int* __restrict__ row_ptr, const uint2* __restrict__ csr,
    const unsigned short* __restrict__ bias,
    const unsigned short* __restrict__ Wf, unsigned short* __restrict__ Hout, int n) {
  constexpr int DW  = FIN / LPG / 2;
  constexpr int NPB = 256 / LPG;
  constexpr int LD  = FIN + 8;
  constexpr int KB  = FIN / 32;
  constexpr int CT  = FOUT / 16;
  constexpr int MT  = NPB / 16;
  __shared__ unsigned short T[NPB * LD];
  const int r = threadIdx.x / LPG, l = threadIdx.x % LPG;
  const int node0 = blockIdx.x * NPB;
  const int g = node0 + r;
  UVec<DW> o;
  #pragma unroll
  for (int d = 0; d < DW; ++d) o.d[d] = 0u;
  if (g < n) {
    float a[2 * DW];
    #pragma unroll
    for (int d = 0; d < 2 * DW; ++d) a[d] = 0.f;
    gather_shfl<DW, LPG>((const unsigned int*)Hin, FIN / 2, csr,
                         row_ptr[g], row_ptr[g + 1], l, a);
    UVec<DW> bb = uload<DW>((const unsigned int*)bias + l * DW);
    #pragma unroll
    for (int d = 0; d < DW; ++d) {
      float lo = fmaxf(a[2*d]   + b2f(bb.d[d] & 0xffffu), 0.f);
      float hi = fmaxf(a[2*d+1] + b2f(bb.d[d] >> 16), 0.f);
      o.d[d] = (unsigned int)f2b(lo) | ((unsigned int)f2b(hi) << 16);
    }
  }
  ustore<DW>((unsigned int*)&T[r * LD + l * DW * 2], o);
  __syncthreads();
  const int w = threadIdx.x >> 6;
  if (w < MT * CT && node0 < n) {
    const int mt = w / CT, ct = w % CT;
    const int ll = threadIdx.x & 63;
    const int r16 = ll & 15, quad = ll >> 4;
    bf8_t afrag[KB], bfrag[KB];
    #pragma unroll
    for (int kb = 0; kb < KB; ++kb) {
      afrag[kb] = *(const bf8_t*)(&T[(mt * 16 + r16) * LD + quad * 8 + kb * 32]);
      bfrag[kb] = *(const bf8_t*)(Wf + ((ct * KB + kb) * 64 + ll) * 8);
    }
    f4_t acc = {0.f, 0.f, 0.f, 0.f};
    #pragma unroll
    for (int kb = 0; kb < KB; ++kb)
      acc = __builtin_amdgcn_mfma_f32_16x16x32_bf16(afrag[kb], bfrag[kb], acc, 0, 0, 0);
    #pragma unroll
    for (int rr = 0; rr < 4; ++rr) {
      int node = node0 + mt * 16 + quad * 4 + rr;
      if (node < n)
        Hout[(size_t)node * FOUT + ct * 16 + r16] = f2b(acc[rr]);
    }
  }
}

// Fused last-layer agg + mean-pool. Full 8-deep direct gather (R16-proven).
__global__ __launch_bounds__(256) void agg_pool_kernel(
    const unsigned short* __restrict__ Hin,
    const int* __restrict__ row_ptr, const uint2* __restrict__ csr,
    const unsigned short* __restrict__ bias,
    const int* __restrict__ batch, float* __restrict__ pooled,
    float* __restrict__ cnt, int n) {
  __shared__ float acc[N_GRAPHS * 16];
  __shared__ float ccnt[N_GRAPHS];
  for (int i = threadIdx.x; i < N_GRAPHS * 16; i += 256) acc[i] = 0.f;
  if (threadIdx.x < N_GRAPHS) ccnt[threadIdx.x] = 0.f;
  __syncthreads();
  const int r = threadIdx.x >> 3, l = threadIdx.x & 7;
  const int g = blockIdx.x * 32 + r;
  if (g < n) {
    const unsigned int* H2 = (const unsigned int*)Hin;
    float a0 = 0.f, a1 = 0.f;
    const int e0 = row_ptr[g], e1 = row_ptr[g + 1];
    for (int base = e0; base < e1; base += 8) {
      uint2 eb[8];
      #pragma unroll
      for (int j = 0; j < 8; ++j)
        eb[j] = csr[(base + j < e1) ? (base + j) : (e1 - 1)];
      float cj[8];
      unsigned int v[8];
      #pragma unroll
      for (int j = 0; j < 8; ++j)
        cj[j] = (base + j < e1) ? __uint_as_float(eb[j].y) : 0.f;
      #pragma unroll
      for (int j = 0; j < 8; ++j)
        v[j] = H2[(size_t)eb[j].x * 8 + l];
      #pragma unroll
      for (int j = 0; j < 8; ++j) {
        a0 = fmaf(b2f(v[j] & 0xffffu), cj[j], a0);
        a1 = fmaf(b2f(v[j] >> 16),     cj[j], a1);
      }
    }
    unsigned int bb = ((const unsigned int*)bias)[l];
    a0 = fmaxf(a0 + b2f(bb & 0xffffu), 0.f);
    a1 = fmaxf(a1 + b2f(bb >> 16), 0.f);
    int gb = batch[g];
    atomicAdd(&acc[gb * 16 + l * 2 + 0], a0);
    atomicAdd(&acc[gb * 16 + l * 2 + 1], a1);
    if (l == 0) atomicAdd(&ccnt[gb], 1.f);
  }
  __syncthreads();
  for (int i = threadIdx.x; i < N_GRAPHS * 16; i += 256)
    if (acc[i] != 0.f) atomicAdd(&pooled[i], acc[i]);
  if (threadIdx.x < N_GRAPHS && ccnt[threadIdx.x] != 0.f)
    atomicAdd(&cnt[threadIdx.x], ccnt[threadIdx.x]);
}

__global__ __launch_bounds__(256) void final_kernel(const float* __restrict__ pooled,
    const float* __restrict__ cnt, const unsigned short* __restrict__ wc,
    void* __restrict__ out, const unsigned int* __restrict__ xraw) {
  int f32;
  block_detect(xraw, nullptr, &f32, nullptr);
  int id = blockIdx.x * 256 + threadIdx.x;
  if (id >= N_GRAPHS * N_CLASSES) return;
  const unsigned short* Wlin = wc + WOFF[8];
  const unsigned short* blin = wc + WOFF[9];
  int g = id / N_CLASSES, c = id - g * N_CLASSES;
  float inv = 1.0f / fmaxf(cnt[g], 1.0f);
  float a = b2f(blin[c]);
  #pragma unroll
  for (int f = 0; f < 16; ++f)
    a = fmaf(pooled[g * 16 + f] * inv, b2f(Wlin[f * N_CLASSES + c]), a);
  if (f32) ((float*)out)[id] = a;
  else     ((unsigned short*)out)[id] = f2b(a);
}

extern "C" void kernel_launch(void* const* d_in, const int* in_sizes, int n_in,
                              void* d_out, int out_size, void* d_ws, size_t ws_size,
                              hipStream_t stream) {
  const unsigned int* xraw = (const unsigned int*)d_in[0];
  const int* eraw          = (const int*)d_in[1];
  const int* braw          = (const int*)d_in[2];

  const int N = in_sizes[2];
  const int E = in_sizes[1] / 2;
  const int nb = (N + 255) / 256;

  char* p = (char*)d_ws;
  auto alloc = [&](size_t bytes) -> void* {
    void* r = (void*)p;
    p += (bytes + 255) & ~(size_t)255;
    return r;
  };
  // zero region: deg | desc | pooled | cnt  (single memset)
  const size_t off_desc = ((size_t)N * 4 + 255) & ~(size_t)255;
  const size_t off_pool = (off_desc + (size_t)nb * 8 + 255) & ~(size_t)255;
  const size_t ztotal   = off_pool + (N_GRAPHS * 16 + N_GRAPHS) * 4;
  char* zbase = (char*)alloc(ztotal);
  int*   deg    = (int*)zbase;
  unsigned long long* desc = (unsigned long long*)(zbase + off_desc);
  float* pooled = (float*)(zbase + off_pool);
  float* cntf   = pooled + N_GRAPHS * 16;

  int*   row_ptr  = (int*)  alloc((size_t)(N + 1) * 4);
  int*   rank     = (int*)  alloc((size_t)E * 4);
  float* dinv     = (float*)alloc((size_t)N * 4);
  int*   batch32  = (int*)  alloc((size_t)N * 4);
  uint2* csr      = (uint2*)alloc((size_t)(E + N + 16) * 8);
  unsigned short* wcan  = (unsigned short*)alloc((size_t)WTOTAL * 2);
  unsigned short* xb    = (unsigned short*)alloc((size_t)N * 128 * 2);
  unsigned short* hbufA = (unsigned short*)alloc((size_t)N * 128 * 2);
  unsigned short* hbufB = (unsigned short*)alloc((size_t)N * 128 * 2);

  hipMemsetAsync(zbase, 0, ztotal, stream);

  WPtrs wp;
  for (int i = 0; i < 10; ++i) wp.p[i] = d_in[3 + i];

  const int BW  = (WTOTAL + 255) / 256;
  const int BB  = nb;
  const int BE  = (E + 255) / 256;
  const int BE2 = (E + 511) / 512;
  const int XC  = (N * 128 + 2047) / 2048;
  cvtwe_kernel<<<BE2 + XC + BW + BB, 256, 0, stream>>>(xraw, wp, wcan,
      braw, batch32, eraw, deg, rank, xb, BE2, XC, BW, N, E);

  scan_kernel<<<nb, 256, 0, stream>>>(deg, row_ptr, dinv, desc, csr, N);

  const unsigned short* b2 = wcan + WOFF[3];
  const unsigned short* W3 = wcan + WOFF[4];
  const unsigned short* b3 = wcan + WOFF[5];
  const unsigned short* W4 = wcan + WOFF[6];
  const unsigned short* b4 = wcan + WOFF[7];

  fill_kernel<<<BE, 256, 0, stream>>>(eraw, xraw, row_ptr, rank, dinv, csr, E);

  aggemm0_kernel<<<(N + 15) / 16, 256, 0, stream>>>(
      xb, row_ptr, csr, wcan, hbufB, N);
  aggemm_kernel<64, 32, 8><<<(N + 31) / 32, 256, 0, stream>>>(
      hbufB, row_ptr, csr, b2, W3, hbufA, N);
  aggemm_kernel<32, 16, 8><<<(N + 31) / 32, 256, 0, stream>>>(
      hbufA, row_ptr, csr, b3, W4, hbufB, N);
  agg_pool_kernel<<<(N + 31) / 32, 256, 0, stream>>>(hbufB, row_ptr, csr, b4,
      batch32, pooled, cntf, N);

  final_kernel<<<(N_GRAPHS * N_CLASSES + 255) / 256, 256, 0, stream>>>(pooled, cntf, wcan, d_out, xraw);
}